// Round 8
// baseline (261.153 us; speedup 1.0000x reference)
//
#include <hip/hip_runtime.h>

// Tree-LSTM AST encoder, complete 8-ary tree, N=100000, D=128, C=8.
// Internal nodes 0..12499 (only 12499 has 7 children), leaves 12500..99999
// (leaf result == emb row), sentinel 100000.
//
// SINGLE persistent kernel (256 blocks x 512 thr, 1 block/CU, co-resident) +
// bar_init. Phases via table: L5 [4681,12500) 245 blks | L4 [585,4681) 128 |
// L3 [73,585) 16 | L2 [9,73) 2 | L1 [1,9) + root, block 0. 4 grid barriers.
//
// R6 failed (275us): builtin MFMA + 128-VGPR cap => compiler rematerialized
// the 32 weight B-fragments from L2 inside every mfma phase. R7 showed "a"
// constraints alone don't stop remat. Fix here: asm("" : "+a"(frag)) after
// the load -- an asm-DEFINED value cannot be rematerialized; it stays pinned
// in AGPRs for the kernel lifetime (128 AGPR + ~100 VGPR <= 256 @ 2 w/SIMD).
//
// Per block: 8 waves; wave w owns dims w*16..+15 for all 4 gates; cell fully
// in registers from MFMA C/D frags (col=lane&15, row=(lane>>4)*4+reg).
// Double-buffered Xh, one intra-block barrier/step, 2-step gather prefetch.
// No prep kernel: blocks build weight frags from fp32 W; gathers cvt fp32 emb.
//
// ws: resultsH f16[12500*128] (3.2MB) | bar unsigned[16]

#define D 128
#define NTOT 100000
#define NINT 12500
#define NB 256

typedef _Float16 f16x8 __attribute__((ext_vector_type(8)));
typedef float    f32x4 __attribute__((ext_vector_type(4)));

__device__ __forceinline__ float fsig(float x) {
    return __builtin_amdgcn_rcpf(1.f + __expf(-x));
}
__device__ __forceinline__ float ftanh(float x) {
    return 1.f - 2.f * __builtin_amdgcn_rcpf(__expf(2.f * x) + 1.f);
}

// B operand pinned in AGPRs; asm-defined values cannot be rematerialized.
#define MFMA_AB(ACC, A, B) \
    asm("v_mfma_f32_16x16x32_f16 %0, %1, %2, %0" : "+v"(ACC) : "v"(A), "a"(B))
#define PIN_AGPR(X) asm("" : "+a"(X))

__global__ void bar_init(unsigned* __restrict__ bar) {
    if (threadIdx.x < 16) bar[threadIdx.x] = 0u;
}

__global__ __launch_bounds__(512) void tree_lstm(
    const float* __restrict__ W_ih, const float* __restrict__ W_hh,
    const float* __restrict__ b_ih, const float* __restrict__ b_hh,
    const float* __restrict__ emb, const int* __restrict__ node_types,
    const int* __restrict__ children,
    _Float16* __restrict__ resultsH, unsigned* __restrict__ bar,
    float* __restrict__ out)
{
    __shared__ __align__(16) _Float16 Xh[2][32][264];  // [buf][node][x(128)|h(128)|pad]
    __shared__ int chid_s[32][8];
    __shared__ int chty_s[32][8];

    const int t    = threadIdx.x;
    const int w    = t >> 6;
    const int l    = t & 63;
    const int bid  = blockIdx.x;
    const int row  = t >> 4;           // gather row (TPR=16)
    const int di   = (t & 15) * 8;     // gather dim offset (DPT=8)
    const int dcol = w * 16 + (l & 15);

    unsigned* cnt  = bar;
    unsigned* flag = bar + 8;
    auto gbar = [&](int slot) {
        __syncthreads();
        if (t == 0) {
            __threadfence();
            unsigned old = __hip_atomic_fetch_add(&cnt[slot], 1u,
                                __ATOMIC_ACQ_REL, __HIP_MEMORY_SCOPE_AGENT);
            if (old == NB - 1) {
                __hip_atomic_store(&flag[slot], 1u,
                                   __ATOMIC_RELEASE, __HIP_MEMORY_SCOPE_AGENT);
            } else {
                while (__hip_atomic_load(&flag[slot],
                           __ATOMIC_ACQUIRE, __HIP_MEMORY_SCOPE_AGENT) == 0u)
                    __builtin_amdgcn_s_sleep(2);
            }
        }
        __syncthreads();
    };

    // ---- weight B-fragments straight from fp32 W; PINNED into AGPRs ----
    // frag(ct,kk): k0=(kk&3)*32+(l>>4)*8, c=ct*128+dcol; B[k][c]=W[c][k]
    f16x8 bf[4][8];
#pragma unroll
    for (int ct = 0; ct < 4; ++ct) {
        const int c = ct * 128 + dcol;
#pragma unroll
        for (int kk = 0; kk < 8; ++kk) {
            const int k0 = (kk & 3) * 32 + ((l >> 4) * 8);
            const float* src = (kk < 4) ? (W_ih + (size_t)c * D + k0)
                                        : (W_hh + (size_t)c * D + k0);
            float4 a = *(const float4*)(src);
            float4 b = *(const float4*)(src + 4);
            f16x8 v;
            v[0]=(_Float16)a.x; v[1]=(_Float16)a.y; v[2]=(_Float16)a.z; v[3]=(_Float16)a.w;
            v[4]=(_Float16)b.x; v[5]=(_Float16)b.y; v[6]=(_Float16)b.z; v[7]=(_Float16)b.w;
            bf[ct][kk] = v;
            PIN_AGPR(bf[ct][kk]);
        }
    }
    float4 bb;
    bb.x = b_ih[dcol      ] + b_hh[dcol      ];
    bb.y = b_ih[dcol + 128] + b_hh[dcol + 128];
    bb.z = b_ih[dcol + 256] + b_hh[dcol + 256];
    bb.w = b_ih[dcol + 384] + b_hh[dcol + 384];

    float cr[2][4], hr[2][4];
    f32x4 acc[2][4];

    auto embf = [&](int ty) -> f16x8 {
        const float* p = emb + (size_t)ty * D + di;
        float4 a = *(const float4*)p;
        float4 b = *(const float4*)(p + 4);
        f16x8 v;
        v[0]=(_Float16)a.x; v[1]=(_Float16)a.y; v[2]=(_Float16)a.z; v[3]=(_Float16)a.w;
        v[4]=(_Float16)b.x; v[5]=(_Float16)b.y; v[6]=(_Float16)b.z; v[7]=(_Float16)b.w;
        return v;
    };

    // One inlined tile body, driven by the phase table (keeps I-cache small).
    auto do_tile = [&](int n0, int B, bool l5chk, bool wres, bool wout) {
        if (t < 256) {
            int rr = t >> 3, slot = t & 7;
            int ch = children[(size_t)(n0 + rr) * 8 + slot];
            chid_s[rr][slot] = ch;
            chty_s[rr][slot] = (ch >= NINT && ch < NTOT) ? node_types[ch] : 0;
        }
        __syncthreads();

        auto gath = [&](int s) -> f16x8 {
            if (s == 0) return embf(node_types[n0 + row]);
            int ch = chid_s[row][s - 1];
            if (ch >= NTOT) return (f16x8)(_Float16)0.f;
            if (ch < NINT)  return *(const f16x8*)(resultsH + (size_t)ch * D + di);
            return embf(chty_s[row][s - 1]);
        };

        *(f16x8*)&Xh[0][row][di]       = gath(0);
        *(f16x8*)&Xh[0][row][128 + di] = (f16x8)(_Float16)0.f;
        f16x8 xA = gath(1);
        f16x8 xB = gath(2);
#pragma unroll
        for (int rt = 0; rt < 2; ++rt)
#pragma unroll
            for (int r = 0; r < 4; ++r) { cr[rt][r] = 0.f; hr[rt][r] = 0.f; }
        __syncthreads();

        for (int s = 0; s < 9; ++s) {
            const int b = s & 1;
            // MFMA: gates[32x512] = Xh[32x256] * Wcat[256x512]
#pragma unroll
            for (int rt = 0; rt < 2; ++rt)
#pragma unroll
                for (int ct = 0; ct < 4; ++ct) acc[rt][ct] = (f32x4){0.f, 0.f, 0.f, 0.f};
#pragma unroll
            for (int kk = 0; kk < 8; ++kk) {
#pragma unroll
                for (int rt = 0; rt < 2; ++rt) {
                    f16x8 a = *(const f16x8*)&Xh[b][rt * 16 + (l & 15)][kk * 32 + ((l >> 4) * 8)];
#pragma unroll
                    for (int ct = 0; ct < 4; ++ct)
                        MFMA_AB(acc[rt][ct], a, bf[ct][kk]);
                }
            }
            if (s < 8) {
                *(f16x8*)&Xh[b ^ 1][row][di] = xA;
                xA = xB;
                if (s <= 5) xB = gath(s + 3);
            }
            // cell fully in registers
#pragma unroll
            for (int rt = 0; rt < 2; ++rt)
#pragma unroll
                for (int r = 0; r < 4; ++r) {
                    const int r2 = rt * 16 + ((l >> 4) * 4) + r;
                    const bool upd = !l5chk || s < 8 || (n0 + r2 != NINT - 1);
                    if (upd) {
                        float iv = fsig (acc[rt][0][r] + bb.x);
                        float fv = fsig (acc[rt][1][r] + bb.y);
                        float gv = ftanh(acc[rt][2][r] + bb.z);
                        float ov = fsig (acc[rt][3][r] + bb.w);
                        float cn = fv * cr[rt][r] + iv * gv;
                        cr[rt][r] = cn;
                        hr[rt][r] = ov * ftanh(cn);
                    }
                    if (s < 8) Xh[b ^ 1][r2][128 + dcol] = (_Float16)hr[rt][r];
                }
            __syncthreads();
        }

#pragma unroll
        for (int rt = 0; rt < 2; ++rt)
#pragma unroll
            for (int r = 0; r < 4; ++r) {
                const int r2 = rt * 16 + ((l >> 4) * 4) + r;
                if (wres && r2 < B)
                    resultsH[(size_t)(n0 + r2) * D + dcol] = (_Float16)hr[rt][r];
            }
        if (wout && (l >> 4) == 0) out[dcol] = hr[0][0];
    };

    // ---- phase table: start, count, nblocks, l5check, wres, wout, barrier ----
    static const int    ph_start[6] = {4681, 585, 73,  9,  1, 0};
    static const int    ph_cnt  [6] = {7819, 4096, 512, 64, 8, 1};
    static const int    ph_nb   [6] = {245, 128, 16,  2,  1, 1};
    static const int    ph_bar  [6] = {1, 1, 1, 1, 0, 0};

    for (int p = 0; p < 6; ++p) {
        if (bid < ph_nb[p]) {
            int n0 = ph_start[p] + bid * 32;
            int B  = min(32, ph_start[p] + ph_cnt[p] - n0);
            do_tile(n0, B, p == 0, p < 5, p == 5);
        }
        if (ph_bar[p]) gbar(p);
    }
}

extern "C" void kernel_launch(void* const* d_in, const int* in_sizes, int n_in,
                              void* d_out, int out_size, void* d_ws, size_t ws_size,
                              hipStream_t stream)
{
    const float* emb        = (const float*)d_in[0];
    const float* W_ih       = (const float*)d_in[1];
    const float* W_hh       = (const float*)d_in[2];
    const float* b_ih       = (const float*)d_in[3];
    const float* b_hh       = (const float*)d_in[4];
    const int*   node_types = (const int*)d_in[5];
    const int*   children   = (const int*)d_in[6];

    float* out = (float*)d_out;

    char*      ws       = (char*)d_ws;
    _Float16*  resultsH = (_Float16*)ws;                        // 3,200,000 B
    size_t     off      = ((size_t)NINT * D * 2 + 255) & ~(size_t)255;
    unsigned*  barp     = (unsigned*)(ws + off);                // 64 B

    bar_init<<<1, 64, 0, stream>>>(barp);
    tree_lstm<<<NB, 512, 0, stream>>>(W_ih, W_hh, b_ih, b_hh, emb, node_types,
                                      children, resultsH, barp, out);
}

// Round 9
// 201.933 us; speedup vs baseline: 1.2933x; 1.2933x over previous
//
#include <hip/hip_runtime.h>

// Tree-LSTM AST encoder, complete 8-ary tree, N=100000, D=128, C=8.
// Internal nodes 0..12499 (only 12499 has 7 children), leaves 12500..99999
// (leaf result == emb row), sentinel 100000.
//
// SINGLE persistent kernel (256 blocks x 512 thr, 1 block/CU, co-resident).
// Phases: L5 [4681,12500) 245 blks | L4 [585,4681) 128 | L3 [73,585) 16
//         | tail in block 0: L2 (2 tiles) + L1 + root. 3 grid barriers.
//
// R8 lesson: ACQUIRE-polling the barrier flag emits buffer_inv (full L1+L2
// invalidate) EVERY poll, on EVERY spinning block -> working blocks ran
// against permanently-cold L2 (MfmaUtil 4.4%, 261us; weight pinning only
// bought 14us). Fix: RELEASE-only arrival, RELAXED spin loads (no inv),
// ONE __threadfence() after the flag flips. Tail runs block-local (a block
// reading its own writes needs no fence) -> one barrier fewer.
//
// Per block: 8 waves; wave w owns dims w*16..+15 for all 4 gates; cell fully
// in registers from MFMA C/D frags (col=lane&15, row=(lane>>4)*4+reg).
// Weight B-fragments AGPR-pinned via asm (cannot be remat'd/spilled):
// 128 AGPR + ~116 VGPR <= 256 unified @ 2 waves/SIMD.
// Double-buffered Xh, one intra-block barrier/step, 2-step gather prefetch.
//
// ws: resultsH f16[12500*128] (3.2MB) | bar unsigned[16]

#define D 128
#define NTOT 100000
#define NINT 12500
#define NB 256

typedef _Float16 f16x8 __attribute__((ext_vector_type(8)));
typedef float    f32x4 __attribute__((ext_vector_type(4)));

__device__ __forceinline__ float fsig(float x) {
    return __builtin_amdgcn_rcpf(1.f + __expf(-x));
}
__device__ __forceinline__ float ftanh(float x) {
    return 1.f - 2.f * __builtin_amdgcn_rcpf(__expf(2.f * x) + 1.f);
}

// B operand pinned in AGPRs; asm-defined values cannot be rematerialized.
#define MFMA_AB(ACC, A, B) \
    asm("v_mfma_f32_16x16x32_f16 %0, %1, %2, %0" : "+v"(ACC) : "v"(A), "a"(B))
#define PIN_AGPR(X) asm("" : "+a"(X))

__global__ void bar_init(unsigned* __restrict__ bar) {
    if (threadIdx.x < 16) bar[threadIdx.x] = 0u;
}

__global__ __launch_bounds__(512) void tree_lstm(
    const float* __restrict__ W_ih, const float* __restrict__ W_hh,
    const float* __restrict__ b_ih, const float* __restrict__ b_hh,
    const float* __restrict__ emb, const int* __restrict__ node_types,
    const int* __restrict__ children,
    _Float16* __restrict__ resultsH, unsigned* __restrict__ bar,
    float* __restrict__ out)
{
    __shared__ __align__(16) _Float16 Xh[2][32][264];  // [buf][node][x(128)|h(128)|pad]
    __shared__ int chid_s[32][8];
    __shared__ int chty_s[32][8];

    const int t    = threadIdx.x;
    const int w    = t >> 6;
    const int l    = t & 63;
    const int bid  = blockIdx.x;
    const int row  = t >> 4;           // gather row (TPR=16)
    const int di   = (t & 15) * 8;     // gather dim offset (DPT=8)
    const int dcol = w * 16 + (l & 15);

    unsigned* cnt  = bar;
    unsigned* flag = bar + 8;

    // Cache-quiet grid barrier: RELEASE arrival (one wbl2, publishes results),
    // RELAXED spin (global_load sc1 -- NO buffer_inv per poll),
    // ONE full fence (inv) after the flag is observed.
    auto gbar = [&](int slot) {
        __syncthreads();
        if (t == 0) {
            unsigned old = __hip_atomic_fetch_add(&cnt[slot], 1u,
                                __ATOMIC_RELEASE, __HIP_MEMORY_SCOPE_AGENT);
            if (old == NB - 1) {
                __hip_atomic_store(&flag[slot], 1u,
                                   __ATOMIC_RELEASE, __HIP_MEMORY_SCOPE_AGENT);
            } else {
                while (__hip_atomic_load(&flag[slot],
                           __ATOMIC_RELAXED, __HIP_MEMORY_SCOPE_AGENT) == 0u)
                    __builtin_amdgcn_s_sleep(8);
            }
            __threadfence();   // single acquire: invalidate L1/L2 once
        }
        __syncthreads();
    };

    // ---- weight B-fragments straight from fp32 W; PINNED into AGPRs ----
    // frag(ct,kk): k0=(kk&3)*32+(l>>4)*8, c=ct*128+dcol; B[k][c]=W[c][k]
    f16x8 bf[4][8];
#pragma unroll
    for (int ct = 0; ct < 4; ++ct) {
        const int c = ct * 128 + dcol;
#pragma unroll
        for (int kk = 0; kk < 8; ++kk) {
            const int k0 = (kk & 3) * 32 + ((l >> 4) * 8);
            const float* src = (kk < 4) ? (W_ih + (size_t)c * D + k0)
                                        : (W_hh + (size_t)c * D + k0);
            float4 a = *(const float4*)(src);
            float4 b = *(const float4*)(src + 4);
            f16x8 v;
            v[0]=(_Float16)a.x; v[1]=(_Float16)a.y; v[2]=(_Float16)a.z; v[3]=(_Float16)a.w;
            v[4]=(_Float16)b.x; v[5]=(_Float16)b.y; v[6]=(_Float16)b.z; v[7]=(_Float16)b.w;
            bf[ct][kk] = v;
            PIN_AGPR(bf[ct][kk]);
        }
    }
    float4 bb;
    bb.x = b_ih[dcol      ] + b_hh[dcol      ];
    bb.y = b_ih[dcol + 128] + b_hh[dcol + 128];
    bb.z = b_ih[dcol + 256] + b_hh[dcol + 256];
    bb.w = b_ih[dcol + 384] + b_hh[dcol + 384];

    float cr[2][4], hr[2][4];
    f32x4 acc[2][4];

    auto embf = [&](int ty) -> f16x8 {
        const float* p = emb + (size_t)ty * D + di;
        float4 a = *(const float4*)p;
        float4 b = *(const float4*)(p + 4);
        f16x8 v;
        v[0]=(_Float16)a.x; v[1]=(_Float16)a.y; v[2]=(_Float16)a.z; v[3]=(_Float16)a.w;
        v[4]=(_Float16)b.x; v[5]=(_Float16)b.y; v[6]=(_Float16)b.z; v[7]=(_Float16)b.w;
        return v;
    };

    auto do_tile = [&](int n0, int B, bool l5chk, bool wres, bool wout) {
        if (t < 256) {
            int rr = t >> 3, slot = t & 7;
            int ch = children[(size_t)(n0 + rr) * 8 + slot];
            chid_s[rr][slot] = ch;
            chty_s[rr][slot] = (ch >= NINT && ch < NTOT) ? node_types[ch] : 0;
        }
        __syncthreads();

        auto gath = [&](int s) -> f16x8 {
            if (s == 0) return embf(node_types[n0 + row]);
            int ch = chid_s[row][s - 1];
            if (ch >= NTOT) return (f16x8)(_Float16)0.f;
            if (ch < NINT)  return *(const f16x8*)(resultsH + (size_t)ch * D + di);
            return embf(chty_s[row][s - 1]);
        };

        *(f16x8*)&Xh[0][row][di]       = gath(0);
        *(f16x8*)&Xh[0][row][128 + di] = (f16x8)(_Float16)0.f;
        f16x8 xA = gath(1);
        f16x8 xB = gath(2);
#pragma unroll
        for (int rt = 0; rt < 2; ++rt)
#pragma unroll
            for (int r = 0; r < 4; ++r) { cr[rt][r] = 0.f; hr[rt][r] = 0.f; }
        __syncthreads();

        for (int s = 0; s < 9; ++s) {
            const int b = s & 1;
            // MFMA: gates[32x512] = Xh[32x256] * Wcat[256x512]
#pragma unroll
            for (int rt = 0; rt < 2; ++rt)
#pragma unroll
                for (int ct = 0; ct < 4; ++ct) acc[rt][ct] = (f32x4){0.f, 0.f, 0.f, 0.f};
#pragma unroll
            for (int kk = 0; kk < 8; ++kk) {
#pragma unroll
                for (int rt = 0; rt < 2; ++rt) {
                    f16x8 a = *(const f16x8*)&Xh[b][rt * 16 + (l & 15)][kk * 32 + ((l >> 4) * 8)];
#pragma unroll
                    for (int ct = 0; ct < 4; ++ct)
                        MFMA_AB(acc[rt][ct], a, bf[ct][kk]);
                }
            }
            if (s < 8) {
                *(f16x8*)&Xh[b ^ 1][row][di] = xA;
                xA = xB;
                if (s <= 5) xB = gath(s + 3);
            }
            // cell fully in registers
#pragma unroll
            for (int rt = 0; rt < 2; ++rt)
#pragma unroll
                for (int r = 0; r < 4; ++r) {
                    const int r2 = rt * 16 + ((l >> 4) * 4) + r;
                    const bool upd = !l5chk || s < 8 || (n0 + r2 != NINT - 1);
                    if (upd) {
                        float iv = fsig (acc[rt][0][r] + bb.x);
                        float fv = fsig (acc[rt][1][r] + bb.y);
                        float gv = ftanh(acc[rt][2][r] + bb.z);
                        float ov = fsig (acc[rt][3][r] + bb.w);
                        float cn = fv * cr[rt][r] + iv * gv;
                        cr[rt][r] = cn;
                        hr[rt][r] = ov * ftanh(cn);
                    }
                    if (s < 8) Xh[b ^ 1][r2][128 + dcol] = (_Float16)hr[rt][r];
                }
            __syncthreads();
        }

#pragma unroll
        for (int rt = 0; rt < 2; ++rt)
#pragma unroll
            for (int r = 0; r < 4; ++r) {
                const int r2 = rt * 16 + ((l >> 4) * 4) + r;
                if (wres && r2 < B)
                    resultsH[(size_t)(n0 + r2) * D + dcol] = (_Float16)hr[rt][r];
            }
        if (wout && (l >> 4) == 0) out[dcol] = hr[0][0];
    };

    // ---- L5: 245 tiles ----
    if (bid < 245) {
        int n0 = 4681 + bid * 32;
        do_tile(n0, min(32, 12500 - n0), true, true, false);
    }
    gbar(0);
    // ---- L4: 128 tiles ----
    if (bid < 128) do_tile(585 + bid * 32, 32, false, true, false);
    gbar(1);
    // ---- L3: 16 tiles ----
    if (bid < 16)  do_tile(73 + bid * 32, 32, false, true, false);
    gbar(2);
    // ---- tail, block-local in block 0 (no fences needed: reads own writes) ----
    if (bid == 0) {
        do_tile( 9, 32, false, true,  false);   // L2 tile 0: nodes 9..40
        do_tile(41, 32, false, true,  false);   // L2 tile 1: nodes 41..72
        do_tile( 1,  8, false, true,  false);   // L1: nodes 1..8
        do_tile( 0,  1, false, false, true);    // root: node 0 -> out
    }
}

extern "C" void kernel_launch(void* const* d_in, const int* in_sizes, int n_in,
                              void* d_out, int out_size, void* d_ws, size_t ws_size,
                              hipStream_t stream)
{
    const float* emb        = (const float*)d_in[0];
    const float* W_ih       = (const float*)d_in[1];
    const float* W_hh       = (const float*)d_in[2];
    const float* b_ih       = (const float*)d_in[3];
    const float* b_hh       = (const float*)d_in[4];
    const int*   node_types = (const int*)d_in[5];
    const int*   children   = (const int*)d_in[6];

    float* out = (float*)d_out;

    char*      ws       = (char*)d_ws;
    _Float16*  resultsH = (_Float16*)ws;                        // 3,200,000 B
    size_t     off      = ((size_t)NINT * D * 2 + 255) & ~(size_t)255;
    unsigned*  barp     = (unsigned*)(ws + off);                // 64 B

    bar_init<<<1, 64, 0, stream>>>(barp);
    tree_lstm<<<NB, 512, 0, stream>>>(W_ih, W_hh, b_ih, b_hh, emb, node_types,
                                      children, resultsH, barp, out);
}